// Round 3
// baseline (322.764 us; speedup 1.0000x reference)
//
#include <hip/hip_runtime.h>

#define NROWS 8192   // N == M == 8192
#define DDIM  512
#define OUTN  8192

typedef int   i32x4  __attribute__((ext_vector_type(4)));
typedef int   i32x8  __attribute__((ext_vector_type(8)));
typedef float f32x16 __attribute__((ext_vector_type(16)));

// ---------------------------------------------------------------------------
// Fragment layout for mfma_scale_f32_32x32x64_f8f6f4 (A and B identical):
// lane l holds row (l&31), k-bytes (l>>5)*32 .. +31 of a 64-k window.
// Storage: off(row,k) = (row>>5)*16384        // 32-row group
//                     + (k>>6)*2048           // 64-k window h = 0..7
//                     + (row&31)*32 + ((k>>5)&1)*1024 + (k&31)   // = lane*32+b
// A wave's 64 lanes read 2 KB contiguous per (group,h): 2x dwordx4/lane.
//
// Prep (UNCHANGED — control variable): one block per 32-row group,
// LDS-staged group image, coalesced 16 KB flush.
// ---------------------------------------------------------------------------
__global__ void __launch_bounds__(256)
rbf_prep(const float* __restrict__ x, const float* __restrict__ y,
         unsigned char* __restrict__ xs, unsigned char* __restrict__ ys,
         float* __restrict__ x2, float* __restrict__ y2) {
    __shared__ unsigned char lbuf[16384];
    const int tid  = threadIdx.x;
    const int lane = tid & 63;
    const int w    = tid >> 6;

    int grp = blockIdx.x;                       // 0..511
    const float* src; unsigned char* dst; float* nrm;
    if (grp < 256) { src = x; dst = xs; nrm = x2; }
    else           { grp -= 256; src = y; dst = ys; nrm = y2; }

    const int loff_base = (lane >> 3) * 2048 + ((lane >> 2) & 1) * 1024 + (lane & 3) * 8;

#pragma unroll
    for (int j = 0; j < 8; ++j) {
        const int r   = w * 8 + j;              // row within group (0..31)
        const int row = grp * 32 + r;
        const float* p = src + (size_t)row * DDIM + lane * 8;
        float4 v0 = *(const float4*)(p);
        float4 v1 = *(const float4*)(p + 4);

        float s = v0.x * v0.x + v0.y * v0.y + v0.z * v0.z + v0.w * v0.w
                + v1.x * v1.x + v1.y * v1.y + v1.z * v1.z + v1.w * v1.w;

        int lo = __builtin_amdgcn_cvt_pk_fp8_f32(v0.x, v0.y, 0, false);
        lo     = __builtin_amdgcn_cvt_pk_fp8_f32(v0.z, v0.w, lo, true);
        int hi = __builtin_amdgcn_cvt_pk_fp8_f32(v1.x, v1.y, 0, false);
        hi     = __builtin_amdgcn_cvt_pk_fp8_f32(v1.z, v1.w, hi, true);

        *(int2*)(lbuf + loff_base + r * 32) = make_int2(lo, hi);

#pragma unroll
        for (int o = 32; o > 0; o >>= 1) s += __shfl_down(s, o, 64);
        if (lane == 0) nrm[row] = s;
    }

    __syncthreads();
    unsigned char* gdst = dst + (size_t)grp * 16384;
#pragma unroll
    for (int it = 0; it < 4; ++it)
        *(i32x4*)(gdst + it * 4096 + tid * 16) =
            *(const i32x4*)(lbuf + it * 4096 + tid * 16);
}

// ---------------------------------------------------------------------------
// R3: GIANT-TILE gemm — halve issued load volume (the one untested lever).
// 256x256 block tile, 4 waves (2x2), each wave computes a FULL 128x128
// quadrant: 4x4 of 32x32x64 MFMAs, acc = 16 x f32x16 (~256 VGPR, ~340 total,
// 1 wave/SIMD via launch_bounds(256,1) on the unified 512-reg file).
// Issued loads: 512 KB per block for 256 KB of output (2:1) vs the previous
// 4:1 — total fragment traffic 1 GiB -> 512 MB, relieving TCC read/write
// contention with the 268 MB HBM store stream. R2 proved the kernel is
// occupancy-insensitive, so 1 wave/SIMD is an acceptable trade.
// Fragment layout, epilogue math unchanged (verified absmax=0 in R1/R2).
// ---------------------------------------------------------------------------
__global__ void __launch_bounds__(256, 1)
rbf_gemm(const unsigned char* __restrict__ xs,
         const unsigned char* __restrict__ ys,
         const float* __restrict__ x2, const float* __restrict__ y2,
         const float* __restrict__ gamma, float* __restrict__ out) {
    const int tid  = threadIdx.x;
    const int lane = tid & 63;
    const int w    = tid >> 6;        // wave 0..3
    const int wm   = w & 1;           // wave row (0..1)
    const int wn   = w >> 1;          // wave col (0..1)

    const int bm = blockIdx.x & 31;   // fast-varying -> consecutive blocks
    const int bn = blockIdx.x >> 5;   //   share the B panel (L2 locality);
                                      //   bm%8 pins each XCD to a 512 KB A set
    const int row0 = bm * 256 + wm * 128;
    const int col0 = bn * 256 + wn * 128;

    f32x16 acc[4][4] = {};

    // fragment base: 32-row group (bm*8 + wm*4 + mi), window h, lane*32
    const unsigned char* abase = xs + (size_t)(bm * 8 + wm * 4) * 16384 + lane * 32;
    const unsigned char* bbase = ys + (size_t)(bn * 8 + wn * 4) * 16384 + lane * 32;

#pragma unroll
    for (int h = 0; h < 8; ++h) {
        i32x8 af[4], bf[4];
#pragma unroll
        for (int mi = 0; mi < 4; ++mi) {
            const unsigned char* p = abase + mi * 16384 + h * 2048;
            i32x4 lo = *(const i32x4*)(p);
            i32x4 hi = *(const i32x4*)(p + 16);
            af[mi] = __builtin_shufflevector(lo, hi, 0, 1, 2, 3, 4, 5, 6, 7);
        }
#pragma unroll
        for (int ni = 0; ni < 4; ++ni) {
            const unsigned char* p = bbase + ni * 16384 + h * 2048;
            i32x4 lo = *(const i32x4*)(p);
            i32x4 hi = *(const i32x4*)(p + 16);
            bf[ni] = __builtin_shufflevector(lo, hi, 0, 1, 2, 3, 4, 5, 6, 7);
        }
#pragma unroll
        for (int mi = 0; mi < 4; ++mi)
#pragma unroll
            for (int ni = 0; ni < 4; ++ni)
                acc[mi][ni] = __builtin_amdgcn_mfma_scale_f32_32x32x64_f8f6f4(
                    af[mi], bf[ni], acc[mi][ni],
                    0, 0,          // cbsz/blgp = fp8 e4m3
                    0, 0x7F,       // A scale = 1.0 (E8M0 127)
                    0, 0x7F);      // B scale = 1.0
    }

    // Epilogue: out[r][c] = exp(-g*(x2[r]+y2[c]-2*xy))
    // C/D layout (32x32): col = lane&31, row = (r&3) + 8*(r>>2) + 4*(lane>>5).
    const float g  = gamma[0];
    const int   rq = (lane >> 5) * 4;   // 0 or 4
    const int   cl = lane & 31;

    float yn[4];
#pragma unroll
    for (int ni = 0; ni < 4; ++ni) yn[ni] = y2[col0 + ni * 32 + cl];

#pragma unroll
    for (int mi = 0; mi < 4; ++mi) {
        const int rbase = row0 + mi * 32;
        // rows touched: rbase + rq + {0..3, 8..11, 16..19, 24..27}
        float4 xn4[4];
#pragma unroll
        for (int q = 0; q < 4; ++q)
            xn4[q] = *(const float4*)(x2 + rbase + rq + q * 8);
#pragma unroll
        for (int ni = 0; ni < 4; ++ni) {
            const int col = col0 + ni * 32 + cl;
#pragma unroll
            for (int r = 0; r < 16; ++r) {
                const int row = rbase + (r & 3) + 8 * (r >> 2) + rq;
                const float s = xn4[r >> 2][r & 3] + yn[ni] - 2.0f * acc[mi][ni][r];
                __builtin_nontemporal_store(__expf(-g * s),
                                            out + (size_t)row * OUTN + col);
            }
        }
    }
}

extern "C" void kernel_launch(void* const* d_in, const int* in_sizes, int n_in,
                              void* d_out, int out_size, void* d_ws, size_t ws_size,
                              hipStream_t stream) {
    const float* x     = (const float*)d_in[0];
    const float* y     = (const float*)d_in[1];
    const float* gamma = (const float*)d_in[2];
    float* out = (float*)d_out;

    // workspace: xs (4 MB, swizzled fp8) | ys (4 MB) | x2 (32 KB) | y2 (32 KB)
    char* ws = (char*)d_ws;
    unsigned char* xs = (unsigned char*)ws;
    unsigned char* ys = (unsigned char*)(ws + (size_t)NROWS * DDIM);
    float* x2 = (float*)(ws + (size_t)NROWS * DDIM * 2);
    float* y2 = (float*)(ws + (size_t)NROWS * DDIM * 2 + NROWS * 4);

    rbf_prep<<<512, 256, 0, stream>>>(x, y, xs, ys, x2, y2);
    rbf_gemm<<<1024, 256, 0, stream>>>(xs, ys, x2, y2, gamma, out);
}

// Round 4
// 296.937 us; speedup vs baseline: 1.0870x; 1.0870x over previous
//
#include <hip/hip_runtime.h>

#define NROWS 8192   // N == M == 8192
#define DDIM  512
#define OUTN  8192

typedef int   i32x4  __attribute__((ext_vector_type(4)));
typedef int   i32x8  __attribute__((ext_vector_type(8)));
typedef float f32x16 __attribute__((ext_vector_type(16)));

// ---------------------------------------------------------------------------
// Fragment layout for mfma_scale_f32_32x32x64_f8f6f4 (A and B identical):
// lane l holds row (l&31), k-bytes (l>>5)*32 .. +31 of a 64-k window.
// Storage: off(row,k) = (row>>5)*16384        // 32-row group
//                     + (k>>6)*2048           // 64-k window h = 0..7
//                     + (row&31)*32 + ((k>>5)&1)*1024 + (k&31)   // = lane*32+b
// A wave's 64 lanes read 2 KB contiguous per (group,h): 2x dwordx4/lane.
//
// Prep (UNCHANGED — control variable): one block per 32-row group,
// LDS-staged group image, coalesced 16 KB flush.
// ---------------------------------------------------------------------------
__global__ void __launch_bounds__(256)
rbf_prep(const float* __restrict__ x, const float* __restrict__ y,
         unsigned char* __restrict__ xs, unsigned char* __restrict__ ys,
         float* __restrict__ x2, float* __restrict__ y2) {
    __shared__ unsigned char lbuf[16384];
    const int tid  = threadIdx.x;
    const int lane = tid & 63;
    const int w    = tid >> 6;

    int grp = blockIdx.x;                       // 0..511
    const float* src; unsigned char* dst; float* nrm;
    if (grp < 256) { src = x; dst = xs; nrm = x2; }
    else           { grp -= 256; src = y; dst = ys; nrm = y2; }

    const int loff_base = (lane >> 3) * 2048 + ((lane >> 2) & 1) * 1024 + (lane & 3) * 8;

#pragma unroll
    for (int j = 0; j < 8; ++j) {
        const int r   = w * 8 + j;              // row within group (0..31)
        const int row = grp * 32 + r;
        const float* p = src + (size_t)row * DDIM + lane * 8;
        float4 v0 = *(const float4*)(p);
        float4 v1 = *(const float4*)(p + 4);

        float s = v0.x * v0.x + v0.y * v0.y + v0.z * v0.z + v0.w * v0.w
                + v1.x * v1.x + v1.y * v1.y + v1.z * v1.z + v1.w * v1.w;

        int lo = __builtin_amdgcn_cvt_pk_fp8_f32(v0.x, v0.y, 0, false);
        lo     = __builtin_amdgcn_cvt_pk_fp8_f32(v0.z, v0.w, lo, true);
        int hi = __builtin_amdgcn_cvt_pk_fp8_f32(v1.x, v1.y, 0, false);
        hi     = __builtin_amdgcn_cvt_pk_fp8_f32(v1.z, v1.w, hi, true);

        *(int2*)(lbuf + loff_base + r * 32) = make_int2(lo, hi);

#pragma unroll
        for (int o = 32; o > 0; o >>= 1) s += __shfl_down(s, o, 64);
        if (lane == 0) nrm[row] = s;
    }

    __syncthreads();
    unsigned char* gdst = dst + (size_t)grp * 16384;
#pragma unroll
    for (int it = 0; it < 4; ++it)
        *(i32x4*)(gdst + it * 4096 + tid * 16) =
            *(const i32x4*)(lbuf + it * 4096 + tid * 16);
}

// ---------------------------------------------------------------------------
// R4: WRITE-CHANNEL FIX. Identical to the R2 kernel (best: 304 µs) except the
// tile-index decode is swapped: bn is now FAST-varying.
//
// Theory: HBM channels interleave on ~256 B units; an output row (32 KB) spans
// all channels, but a narrow column stripe at fixed cols maps to a FIXED small
// channel subset (row stride is a multiple of the interleave span). With bm
// fast-varying (R0-R3), all concurrent blocks shared bn -> the whole device
// funneled its NT stores into a 512 B-wide column stripe = ~1/16 of the
// channels -> write serialization. That single bottleneck explains R2's
// occupancy/ILP null and R3's load-volume null. With bn fast-varying,
// concurrent blocks cover 128 FULL rows x all 8192 cols = 4 MB contiguous,
// draining across every channel like the 6.4 TB/s harness fill does.
// Read side is unaffected: entire fp8 working set is 8 MB, L2/L3-resident.
// ---------------------------------------------------------------------------
__global__ void __launch_bounds__(256, 4)
rbf_gemm(const unsigned char* __restrict__ xs,
         const unsigned char* __restrict__ ys,
         const float* __restrict__ x2, const float* __restrict__ y2,
         const float* __restrict__ gamma, float* __restrict__ out) {
    const int tid  = threadIdx.x;
    const int lane = tid & 63;
    const int w    = tid >> 6;        // wave 0..3
    const int wm   = w & 1;           // wave row (0..1)
    const int wn   = w >> 1;          // wave col (0..1)

    const int bn = blockIdx.x & 63;   // FAST-varying -> concurrent blocks
    const int bm = blockIdx.x >> 6;   //   spread over all column panels
    const int row0 = bm * 128;
    const int col0 = bn * 128;

    f32x16 acc[2][2] = {};

    const unsigned char* pa0 = xs + (size_t)(bm * 4 + wm * 2) * 16384 + lane * 32;
    const unsigned char* pa1 = pa0 + 16384;
    const unsigned char* pb0 = ys + (size_t)(bn * 4 + wn * 2) * 16384 + lane * 32;
    const unsigned char* pb1 = pb0 + 16384;

#pragma unroll
    for (int h = 0; h < 8; ++h) {
        i32x4 a0l = *(const i32x4*)(pa0);
        i32x4 a0h = *(const i32x4*)(pa0 + 16);
        i32x4 a1l = *(const i32x4*)(pa1);
        i32x4 a1h = *(const i32x4*)(pa1 + 16);
        i32x4 b0l = *(const i32x4*)(pb0);
        i32x4 b0h = *(const i32x4*)(pb0 + 16);
        i32x4 b1l = *(const i32x4*)(pb1);
        i32x4 b1h = *(const i32x4*)(pb1 + 16);
        i32x8 a0 = __builtin_shufflevector(a0l, a0h, 0, 1, 2, 3, 4, 5, 6, 7);
        i32x8 a1 = __builtin_shufflevector(a1l, a1h, 0, 1, 2, 3, 4, 5, 6, 7);
        i32x8 b0 = __builtin_shufflevector(b0l, b0h, 0, 1, 2, 3, 4, 5, 6, 7);
        i32x8 b1 = __builtin_shufflevector(b1l, b1h, 0, 1, 2, 3, 4, 5, 6, 7);

        __builtin_amdgcn_s_setprio(1);
        acc[0][0] = __builtin_amdgcn_mfma_scale_f32_32x32x64_f8f6f4(
            a0, b0, acc[0][0], 0, 0, 0, 0x7F, 0, 0x7F);
        acc[0][1] = __builtin_amdgcn_mfma_scale_f32_32x32x64_f8f6f4(
            a0, b1, acc[0][1], 0, 0, 0, 0x7F, 0, 0x7F);
        acc[1][0] = __builtin_amdgcn_mfma_scale_f32_32x32x64_f8f6f4(
            a1, b0, acc[1][0], 0, 0, 0, 0x7F, 0, 0x7F);
        acc[1][1] = __builtin_amdgcn_mfma_scale_f32_32x32x64_f8f6f4(
            a1, b1, acc[1][1], 0, 0, 0, 0x7F, 0, 0x7F);
        __builtin_amdgcn_s_setprio(0);

        pa0 += 2048; pa1 += 2048; pb0 += 2048; pb1 += 2048;
    }

    // Epilogue: out[r][c] = exp(-g*(x2[r]+y2[c]-2*xy))
    // C/D layout (32x32): col = lane&31, row = (r&3) + 8*(r>>2) + 4*(lane>>5).
    const float g  = gamma[0];
    const int   rq = (lane >> 5) * 4;   // 0 or 4
    const int   cl = lane & 31;
#pragma unroll
    for (int mi = 0; mi < 2; ++mi) {
        const int rbase = row0 + wm * 64 + mi * 32;
        // rows touched: rbase + rq + {0..3, 8..11, 16..19, 24..27}
        float4 xn4[4];
#pragma unroll
        for (int q = 0; q < 4; ++q)
            xn4[q] = *(const float4*)(x2 + rbase + rq + q * 8);
#pragma unroll
        for (int ni = 0; ni < 2; ++ni) {
            const int col = col0 + wn * 64 + ni * 32 + cl;
            const float yn = y2[col];
#pragma unroll
            for (int r = 0; r < 16; ++r) {
                const int row = rbase + (r & 3) + 8 * (r >> 2) + rq;
                const float s = xn4[r >> 2][r & 3] + yn - 2.0f * acc[mi][ni][r];
                __builtin_nontemporal_store(__expf(-g * s),
                                            out + (size_t)row * OUTN + col);
            }
        }
    }
}

extern "C" void kernel_launch(void* const* d_in, const int* in_sizes, int n_in,
                              void* d_out, int out_size, void* d_ws, size_t ws_size,
                              hipStream_t stream) {
    const float* x     = (const float*)d_in[0];
    const float* y     = (const float*)d_in[1];
    const float* gamma = (const float*)d_in[2];
    float* out = (float*)d_out;

    // workspace: xs (4 MB, swizzled fp8) | ys (4 MB) | x2 (32 KB) | y2 (32 KB)
    char* ws = (char*)d_ws;
    unsigned char* xs = (unsigned char*)ws;
    unsigned char* ys = (unsigned char*)(ws + (size_t)NROWS * DDIM);
    float* x2 = (float*)(ws + (size_t)NROWS * DDIM * 2);
    float* y2 = (float*)(ws + (size_t)NROWS * DDIM * 2 + NROWS * 4);

    rbf_prep<<<512, 256, 0, stream>>>(x, y, xs, ys, x2, y2);
    rbf_gemm<<<4096, 256, 0, stream>>>(xs, ys, x2, y2, gamma, out);
}